// Round 1
// baseline (546.694 us; speedup 1.0000x reference)
//
#include <hip/hip_runtime.h>
#include <math.h>

// ---------------------------------------------------------------------------
// CSR construction
// ---------------------------------------------------------------------------
__global__ __launch_bounds__(256) void k_deg_init(int* __restrict__ deg, int N) {
    int i = blockIdx.x * 256 + threadIdx.x;
    if (i < N) deg[i] = 1;  // self-loop
}

__global__ __launch_bounds__(256) void k_count(const int* __restrict__ dst, int E,
                                               int* __restrict__ deg) {
    int e = blockIdx.x * 256 + threadIdx.x;
    if (e < E) atomicAdd(&deg[dst[e]], 1);
}

// single-block exclusive scan (wave-shuffle based), writes rowptr[N+1] and cursor[N]
__global__ __launch_bounds__(1024) void k_scan(const int* __restrict__ deg,
                                               int* __restrict__ rowptr,
                                               int* __restrict__ cursor, int N) {
    __shared__ int wsum[17];
    int t = threadIdx.x;
    int lane = t & 63;
    int wid = t >> 6;
    int carry = 0;
    for (int base = 0; base < N; base += 1024) {
        int idx = base + t;
        int v = (idx < N) ? deg[idx] : 0;
        int x = v;
        #pragma unroll
        for (int off = 1; off < 64; off <<= 1) {
            int y = __shfl_up(x, off, 64);
            if (lane >= off) x += y;
        }
        if (lane == 63) wsum[wid] = x;
        __syncthreads();
        if (wid == 0 && lane < 16) {
            int w = wsum[lane];
            int xs = w;
            #pragma unroll
            for (int off = 1; off < 16; off <<= 1) {
                int y = __shfl_up(xs, off, 64);
                if (lane >= off) xs += y;
            }
            wsum[lane] = xs - w;          // exclusive wave offset
            if (lane == 15) wsum[16] = xs; // chunk total
        }
        __syncthreads();
        int incl = x + wsum[wid];
        if (idx < N) {
            int excl = carry + incl - v;
            rowptr[idx] = excl;
            cursor[idx] = excl;
        }
        int total = wsum[16];
        __syncthreads();  // protect wsum before next chunk
        carry += total;
    }
    if (t == 0) rowptr[N] = carry;
}

__global__ __launch_bounds__(256) void k_scatter(const int* __restrict__ src,
                                                 const int* __restrict__ dst,
                                                 int E, int N,
                                                 int* __restrict__ cursor,
                                                 int* __restrict__ col) {
    int idx = blockIdx.x * 256 + threadIdx.x;
    if (idx < E) {
        int d = dst[idx];
        int pos = atomicAdd(&cursor[d], 1);
        col[pos] = src[idx];
    } else if (idx < E + N) {
        int i = idx - E;
        int pos = atomicAdd(&cursor[i], 1);
        col[pos] = i;  // self loop
    }
}

// ---------------------------------------------------------------------------
// f32 GEMM: C[M,NC] = A[M,K] @ W[K,NC] + bias  (64x64 tile, BK=16, 4x4/thread)
// ---------------------------------------------------------------------------
__global__ __launch_bounds__(256) void gemm_bias(const float* __restrict__ A,
                                                 const float* __restrict__ W,
                                                 const float* __restrict__ bias,
                                                 float* __restrict__ C,
                                                 int M, int K, int NC) {
    __shared__ float As[16][68];  // [k][m], padded
    __shared__ float Bs[16][68];  // [k][n], padded
    int tid = threadIdx.x;
    int tx = tid & 15, ty = tid >> 4;
    int m0 = blockIdx.x * 64, n0 = blockIdx.y * 64;
    float acc[4][4] = {};
    for (int k0 = 0; k0 < K; k0 += 16) {
        #pragma unroll
        for (int i = 0; i < 4; ++i) {
            int idx = tid + i * 256;     // 0..1023 = 64 rows x 16 k
            int r = idx >> 4, c = idx & 15;
            int row = m0 + r;
            As[c][r] = (row < M) ? A[(size_t)row * K + k0 + c] : 0.f;
        }
        #pragma unroll
        for (int i = 0; i < 4; ++i) {
            int idx = tid + i * 256;     // 16 k x 64 n
            int r = idx >> 6, c = idx & 63;
            Bs[r][c] = W[(size_t)(k0 + r) * NC + n0 + c];
        }
        __syncthreads();
        #pragma unroll
        for (int k = 0; k < 16; ++k) {
            float a[4], b[4];
            #pragma unroll
            for (int i = 0; i < 4; ++i) a[i] = As[k][ty * 4 + i];
            #pragma unroll
            for (int i = 0; i < 4; ++i) b[i] = Bs[k][tx * 4 + i];
            #pragma unroll
            for (int i = 0; i < 4; ++i)
                #pragma unroll
                for (int j = 0; j < 4; ++j) acc[i][j] += a[i] * b[j];
        }
        __syncthreads();
    }
    #pragma unroll
    for (int i = 0; i < 4; ++i) {
        int row = m0 + ty * 4 + i;
        if (row < M) {
            #pragma unroll
            for (int j = 0; j < 4; ++j) {
                int cn = n0 + tx * 4 + j;
                C[(size_t)row * NC + cn] = acc[i][j] + bias[cn];
            }
        }
    }
}

// ---------------------------------------------------------------------------
// GATv2 aggregation, H=4, C=64 (layers 1,2): one wave per node, online softmax
// lane l: head h=l>>4, covers c = (l&15)*4 .. +3 (float4)
// ---------------------------------------------------------------------------
__global__ __launch_bounds__(256) void gat_agg4(const float* __restrict__ xl,
                                                const float* __restrict__ xr,
                                                const float* __restrict__ att,
                                                const float* __restrict__ bias,
                                                const int* __restrict__ rowptr,
                                                const int* __restrict__ col,
                                                float* __restrict__ out, int N) {
    int wave = blockIdx.x * 4 + (threadIdx.x >> 6);
    int lane = threadIdx.x & 63;
    if (wave >= N) return;
    const int i = wave;
    const float4 xr4 = *(const float4*)(xr + (size_t)i * 256 + lane * 4);
    const float4 at4 = *(const float4*)(att + lane * 4);  // att[h][c] flattened
    float m = -INFINITY, ssum = 0.f;
    float4 acc = make_float4(0.f, 0.f, 0.f, 0.f);
    int e0 = rowptr[i], e1 = rowptr[i + 1];
    for (int e = e0; e < e1; ++e) {
        int j = col[e];
        float4 g = *(const float4*)(xl + (size_t)j * 256 + lane * 4);
        float t0 = g.x + xr4.x, t1 = g.y + xr4.y, t2 = g.z + xr4.z, t3 = g.w + xr4.w;
        t0 = t0 > 0.f ? t0 : 0.2f * t0;
        t1 = t1 > 0.f ? t1 : 0.2f * t1;
        t2 = t2 > 0.f ? t2 : 0.2f * t2;
        t3 = t3 > 0.f ? t3 : 0.2f * t3;
        float partial = t0 * at4.x + t1 * at4.y + t2 * at4.z + t3 * at4.w;
        partial += __shfl_xor(partial, 1);
        partial += __shfl_xor(partial, 2);
        partial += __shfl_xor(partial, 4);
        partial += __shfl_xor(partial, 8);
        float sc = partial;  // score for this head, uniform in 16-lane group
        if (sc > m) {
            float f = __expf(m - sc);  // m=-inf on first edge -> f=0
            ssum *= f;
            acc.x *= f; acc.y *= f; acc.z *= f; acc.w *= f;
            m = sc;
        }
        float p = __expf(sc - m);
        ssum += p;
        acc.x += p * g.x; acc.y += p * g.y; acc.z += p * g.z; acc.w += p * g.w;
    }
    float inv = 1.f / (ssum + 1e-16f);
    const float4 bv = *(const float4*)(bias + lane * 4);
    float o0 = acc.x * inv + bv.x;
    float o1 = acc.y * inv + bv.y;
    float o2 = acc.z * inv + bv.z;
    float o3 = acc.w * inv + bv.w;
    // ELU
    o0 = o0 > 0.f ? o0 : __expf(o0) - 1.f;
    o1 = o1 > 0.f ? o1 : __expf(o1) - 1.f;
    o2 = o2 > 0.f ? o2 : __expf(o2) - 1.f;
    o3 = o3 > 0.f ? o3 : __expf(o3) - 1.f;
    *(float4*)(out + (size_t)i * 256 + lane * 4) = make_float4(o0, o1, o2, o3);
}

// ---------------------------------------------------------------------------
// GATv2 aggregation H=1, C=64 (layer 3) fused with final FC [64 -> 2]
// one wave per node, lane l <-> channel c=l
// ---------------------------------------------------------------------------
__global__ __launch_bounds__(256) void gat_agg1_fc(const float* __restrict__ xl,
                                                   const float* __restrict__ xr,
                                                   const float* __restrict__ att,
                                                   const float* __restrict__ bias,
                                                   const float* __restrict__ Wfc,
                                                   const float* __restrict__ bfc,
                                                   const int* __restrict__ rowptr,
                                                   const int* __restrict__ col,
                                                   float* __restrict__ out, int N) {
    int wave = blockIdx.x * 4 + (threadIdx.x >> 6);
    int lane = threadIdx.x & 63;
    if (wave >= N) return;
    const int i = wave;
    float xrv = xr[(size_t)i * 64 + lane];
    float atv = att[lane];
    float m = -INFINITY, ssum = 0.f, acc = 0.f;
    int e0 = rowptr[i], e1 = rowptr[i + 1];
    for (int e = e0; e < e1; ++e) {
        int j = col[e];
        float g = xl[(size_t)j * 64 + lane];
        float t = g + xrv;
        t = t > 0.f ? t : 0.2f * t;
        float partial = t * atv;
        partial += __shfl_xor(partial, 1);
        partial += __shfl_xor(partial, 2);
        partial += __shfl_xor(partial, 4);
        partial += __shfl_xor(partial, 8);
        partial += __shfl_xor(partial, 16);
        partial += __shfl_xor(partial, 32);
        float sc = partial;
        if (sc > m) {
            float f = __expf(m - sc);
            ssum *= f;
            acc *= f;
            m = sc;
        }
        float p = __expf(sc - m);
        ssum += p;
        acc += p * g;
    }
    float h = acc / (ssum + 1e-16f) + bias[lane];
    // FC: out[i, j] = sum_c h[c] * Wfc[c,j] + bfc[j]
    float r0 = h * Wfc[lane * 2 + 0];
    float r1 = h * Wfc[lane * 2 + 1];
    #pragma unroll
    for (int off = 1; off < 64; off <<= 1) {
        r0 += __shfl_xor(r0, off);
        r1 += __shfl_xor(r1, off);
    }
    if (lane == 0) {
        out[(size_t)i * 2 + 0] = r0 + bfc[0];
        out[(size_t)i * 2 + 1] = r1 + bfc[1];
    }
}

// ---------------------------------------------------------------------------
extern "C" void kernel_launch(void* const* d_in, const int* in_sizes, int n_in,
                              void* d_out, int out_size, void* d_ws, size_t ws_size,
                              hipStream_t stream) {
    const float* x    = (const float*)d_in[0];
    const int*   ei   = (const int*)d_in[1];
    const float* Wl1  = (const float*)d_in[2];
    const float* bl1  = (const float*)d_in[3];
    const float* Wr1  = (const float*)d_in[4];
    const float* br1  = (const float*)d_in[5];
    const float* att1 = (const float*)d_in[6];
    const float* b1   = (const float*)d_in[7];
    const float* Wl2  = (const float*)d_in[8];
    const float* bl2  = (const float*)d_in[9];
    const float* Wr2  = (const float*)d_in[10];
    const float* br2  = (const float*)d_in[11];
    const float* att2 = (const float*)d_in[12];
    const float* b2   = (const float*)d_in[13];
    const float* Wl3  = (const float*)d_in[14];
    const float* bl3  = (const float*)d_in[15];
    const float* Wr3  = (const float*)d_in[16];
    const float* br3  = (const float*)d_in[17];
    const float* att3 = (const float*)d_in[18];
    const float* b3   = (const float*)d_in[19];
    const float* Wfc  = (const float*)d_in[20];
    const float* bfc  = (const float*)d_in[21];
    float* out = (float*)d_out;

    const int N = in_sizes[0] / 16;   // 30000
    const int E = in_sizes[1] / 2;    // 480000
    const int* srcp = ei;
    const int* dstp = ei + E;

    char* ws = (char*)d_ws;
    size_t off = 0;
    auto take = [&](size_t bytes) -> char* {
        char* p = ws + off;
        off = (off + bytes + 255) & ~(size_t)255;
        return p;
    };
    int* rowptr = (int*)take((size_t)(N + 1) * 4);
    int* cursor = (int*)take((size_t)N * 4);
    int* deg    = (int*)take((size_t)N * 4);
    int* col    = (int*)take((size_t)(E + N) * 4);
    float* xl   = (float*)take((size_t)N * 256 * 4);
    float* xr   = (float*)take((size_t)N * 256 * 4);
    float* h    = (float*)take((size_t)N * 256 * 4);
    (void)ws_size; (void)n_in; (void)out_size;

    // CSR build
    k_deg_init<<<dim3((N + 255) / 256), dim3(256), 0, stream>>>(deg, N);
    k_count<<<dim3((E + 255) / 256), dim3(256), 0, stream>>>(dstp, E, deg);
    k_scan<<<dim3(1), dim3(1024), 0, stream>>>(deg, rowptr, cursor, N);
    k_scatter<<<dim3((E + N + 255) / 256), dim3(256), 0, stream>>>(srcp, dstp, E, N, cursor, col);

    dim3 gemm_blk(256);
    dim3 agg_grid((N + 3) / 4);

    // layer 1: x[N,16] -> xl,xr [N,256]
    gemm_bias<<<dim3((N + 63) / 64, 4), gemm_blk, 0, stream>>>(x, Wl1, bl1, xl, N, 16, 256);
    gemm_bias<<<dim3((N + 63) / 64, 4), gemm_blk, 0, stream>>>(x, Wr1, br1, xr, N, 16, 256);
    gat_agg4<<<agg_grid, dim3(256), 0, stream>>>(xl, xr, att1, b1, rowptr, col, h, N);

    // layer 2: h[N,256] -> xl,xr [N,256]
    gemm_bias<<<dim3((N + 63) / 64, 4), gemm_blk, 0, stream>>>(h, Wl2, bl2, xl, N, 256, 256);
    gemm_bias<<<dim3((N + 63) / 64, 4), gemm_blk, 0, stream>>>(h, Wr2, br2, xr, N, 256, 256);
    gat_agg4<<<agg_grid, dim3(256), 0, stream>>>(xl, xr, att2, b2, rowptr, col, h, N);

    // layer 3: h[N,256] -> xl,xr [N,64]; agg + FC -> out [N,2]
    gemm_bias<<<dim3((N + 63) / 64, 1), gemm_blk, 0, stream>>>(h, Wl3, bl3, xl, N, 256, 64);
    gemm_bias<<<dim3((N + 63) / 64, 1), gemm_blk, 0, stream>>>(h, Wr3, br3, xr, N, 256, 64);
    gat_agg1_fc<<<agg_grid, dim3(256), 0, stream>>>(xl, xr, att3, b3, Wfc, bfc, rowptr, col, out, N);
}

// Round 2
// 457.986 us; speedup vs baseline: 1.1937x; 1.1937x over previous
//
#include <hip/hip_runtime.h>
#include <math.h>

typedef __attribute__((ext_vector_type(8))) short bf16x8;
typedef __attribute__((ext_vector_type(4))) float f32x4;

__device__ inline unsigned short f2bf(float f) {
    union { float f; unsigned u; } v; v.f = f;
    unsigned r = v.u + 0x7FFFu + ((v.u >> 16) & 1u);
    return (unsigned short)(r >> 16);
}
__device__ inline float bf2f(unsigned short s) {
    union { unsigned u; float f; } v; v.u = ((unsigned)s) << 16;
    return v.f;
}

// ---------------------------------------------------------------------------
// CSR construction (unchanged, verified)
// ---------------------------------------------------------------------------
__global__ __launch_bounds__(256) void k_deg_init(int* __restrict__ deg, int N) {
    int i = blockIdx.x * 256 + threadIdx.x;
    if (i < N) deg[i] = 1;  // self-loop
}

__global__ __launch_bounds__(256) void k_count(const int* __restrict__ dst, int E,
                                               int* __restrict__ deg) {
    int e = blockIdx.x * 256 + threadIdx.x;
    if (e < E) atomicAdd(&deg[dst[e]], 1);
}

__global__ __launch_bounds__(1024) void k_scan(const int* __restrict__ deg,
                                               int* __restrict__ rowptr,
                                               int* __restrict__ cursor, int N) {
    __shared__ int wsum[17];
    int t = threadIdx.x;
    int lane = t & 63;
    int wid = t >> 6;
    int carry = 0;
    for (int base = 0; base < N; base += 1024) {
        int idx = base + t;
        int v = (idx < N) ? deg[idx] : 0;
        int x = v;
        #pragma unroll
        for (int off = 1; off < 64; off <<= 1) {
            int y = __shfl_up(x, off, 64);
            if (lane >= off) x += y;
        }
        if (lane == 63) wsum[wid] = x;
        __syncthreads();
        if (wid == 0 && lane < 16) {
            int w = wsum[lane];
            int xs = w;
            #pragma unroll
            for (int off = 1; off < 16; off <<= 1) {
                int y = __shfl_up(xs, off, 64);
                if (lane >= off) xs += y;
            }
            wsum[lane] = xs - w;
            if (lane == 15) wsum[16] = xs;
        }
        __syncthreads();
        int incl = x + wsum[wid];
        if (idx < N) {
            int excl = carry + incl - v;
            rowptr[idx] = excl;
            cursor[idx] = excl;
        }
        int total = wsum[16];
        __syncthreads();
        carry += total;
    }
    if (t == 0) rowptr[N] = carry;
}

__global__ __launch_bounds__(256) void k_scatter(const int* __restrict__ src,
                                                 const int* __restrict__ dst,
                                                 int E, int N,
                                                 int* __restrict__ cursor,
                                                 int* __restrict__ col) {
    int idx = blockIdx.x * 256 + threadIdx.x;
    if (idx < E) {
        int d = dst[idx];
        int pos = atomicAdd(&cursor[d], 1);
        col[pos] = src[idx];
    } else if (idx < E + N) {
        int i = idx - E;
        int pos = atomicAdd(&cursor[i], 1);
        col[pos] = i;
    }
}

// ---------------------------------------------------------------------------
// f32 GEMM (kept for layer 1, K=16): C[M,NC] = A @ W + bias
// ---------------------------------------------------------------------------
__global__ __launch_bounds__(256) void gemm_bias(const float* __restrict__ A,
                                                 const float* __restrict__ W,
                                                 const float* __restrict__ bias,
                                                 float* __restrict__ C,
                                                 int M, int K, int NC) {
    __shared__ float As[16][68];
    __shared__ float Bs[16][68];
    int tid = threadIdx.x;
    int tx = tid & 15, ty = tid >> 4;
    int m0 = blockIdx.x * 64, n0 = blockIdx.y * 64;
    float acc[4][4] = {};
    for (int k0 = 0; k0 < K; k0 += 16) {
        #pragma unroll
        for (int i = 0; i < 4; ++i) {
            int idx = tid + i * 256;
            int r = idx >> 4, c = idx & 15;
            int row = m0 + r;
            As[c][r] = (row < M) ? A[(size_t)row * K + k0 + c] : 0.f;
        }
        #pragma unroll
        for (int i = 0; i < 4; ++i) {
            int idx = tid + i * 256;
            int r = idx >> 6, c = idx & 63;
            Bs[r][c] = W[(size_t)(k0 + r) * NC + n0 + c];
        }
        __syncthreads();
        #pragma unroll
        for (int k = 0; k < 16; ++k) {
            float a[4], b[4];
            #pragma unroll
            for (int i = 0; i < 4; ++i) a[i] = As[k][ty * 4 + i];
            #pragma unroll
            for (int i = 0; i < 4; ++i) b[i] = Bs[k][tx * 4 + i];
            #pragma unroll
            for (int i = 0; i < 4; ++i)
                #pragma unroll
                for (int j = 0; j < 4; ++j) acc[i][j] += a[i] * b[j];
        }
        __syncthreads();
    }
    #pragma unroll
    for (int i = 0; i < 4; ++i) {
        int row = m0 + ty * 4 + i;
        if (row < M) {
            #pragma unroll
            for (int j = 0; j < 4; ++j) {
                int cn = n0 + tx * 4 + j;
                C[(size_t)row * NC + cn] = acc[i][j] + bias[cn];
            }
        }
    }
}

// ---------------------------------------------------------------------------
// bf16x3 split MFMA GEMM (K multiple of 32): C = A @ W + bias, ~fp32 accuracy
// BM=128, BN=64, BK=32; 4 waves as 2x2; per wave 64x32 out = 4x2 16x16 frags.
// A,B staged as bf16 hi/lo pairs; identical k-ordering for A and B fragments
// makes the result invariant to the HW's within-chunk k->element mapping.
// ---------------------------------------------------------------------------
#define BM 128
#define BN 64
#define BKK 32
#define LDK 40

__global__ __launch_bounds__(256) void gemm_mfma(const float* __restrict__ A,
                                                 const float* __restrict__ W,
                                                 const float* __restrict__ bias,
                                                 float* __restrict__ C,
                                                 int M, int K, int NC) {
    __shared__ unsigned short Ah[BM * LDK], Al[BM * LDK];
    __shared__ unsigned short Bh[BN * LDK], Bl[BN * LDK];
    int tid = threadIdx.x;
    int lane = tid & 63;
    int wid = tid >> 6;
    int m0 = blockIdx.x * BM;
    int n0 = blockIdx.y * BN;
    int wm = (wid >> 1) * 64;
    int wn = (wid & 1) * 32;
    int r16 = lane & 15;
    int g8 = (lane >> 4) * 8;

    f32x4 acc[4][2];
    #pragma unroll
    for (int a = 0; a < 4; ++a)
        #pragma unroll
        for (int b = 0; b < 2; ++b)
            #pragma unroll
            for (int q = 0; q < 4; ++q) acc[a][b][q] = 0.f;

    for (int k0 = 0; k0 < K; k0 += BKK) {
        // stage A tile: BM x 32 f32 -> hi/lo bf16
        #pragma unroll
        for (int p = 0; p < 4; ++p) {
            int r = (tid >> 3) + 32 * p;
            int kq = (tid & 7) * 4;
            int row = m0 + r;
            float4 v = make_float4(0.f, 0.f, 0.f, 0.f);
            if (row < M) v = *(const float4*)(A + (size_t)row * K + k0 + kq);
            ushort4 hv, lv;
            hv.x = f2bf(v.x); lv.x = f2bf(v.x - bf2f(hv.x));
            hv.y = f2bf(v.y); lv.y = f2bf(v.y - bf2f(hv.y));
            hv.z = f2bf(v.z); lv.z = f2bf(v.z - bf2f(hv.z));
            hv.w = f2bf(v.w); lv.w = f2bf(v.w - bf2f(hv.w));
            *(ushort4*)&Ah[r * LDK + kq] = hv;
            *(ushort4*)&Al[r * LDK + kq] = lv;
        }
        // stage B tile: 32 x BN f32, transposed to [n][k]
        #pragma unroll
        for (int p = 0; p < 2; ++p) {
            int kr = (tid >> 4) + 16 * p;
            int nq = (tid & 15) * 4;
            float4 v = *(const float4*)(W + (size_t)(k0 + kr) * NC + n0 + nq);
            #pragma unroll
            for (int q = 0; q < 4; ++q) {
                float f = (&v.x)[q];
                unsigned short h = f2bf(f);
                Bh[(nq + q) * LDK + kr] = h;
                Bl[(nq + q) * LDK + kr] = f2bf(f - bf2f(h));
            }
        }
        __syncthreads();
        bf16x8 ah[4], al[4], bh[2], bl[2];
        #pragma unroll
        for (int mf = 0; mf < 4; ++mf) {
            int base = (wm + mf * 16 + r16) * LDK + g8;
            ah[mf] = *(const bf16x8*)&Ah[base];
            al[mf] = *(const bf16x8*)&Al[base];
        }
        #pragma unroll
        for (int nf = 0; nf < 2; ++nf) {
            int base = (wn + nf * 16 + r16) * LDK + g8;
            bh[nf] = *(const bf16x8*)&Bh[base];
            bl[nf] = *(const bf16x8*)&Bl[base];
        }
        #pragma unroll
        for (int mf = 0; mf < 4; ++mf)
            #pragma unroll
            for (int nf = 0; nf < 2; ++nf) {
                acc[mf][nf] = __builtin_amdgcn_mfma_f32_16x16x32_bf16(ah[mf], bh[nf], acc[mf][nf], 0, 0, 0);
                acc[mf][nf] = __builtin_amdgcn_mfma_f32_16x16x32_bf16(ah[mf], bl[nf], acc[mf][nf], 0, 0, 0);
                acc[mf][nf] = __builtin_amdgcn_mfma_f32_16x16x32_bf16(al[mf], bh[nf], acc[mf][nf], 0, 0, 0);
            }
        __syncthreads();
    }
    // epilogue: C/D layout col=lane&15, row=(lane>>4)*4+reg (HW-verified)
    int g = lane >> 4;
    #pragma unroll
    for (int nf = 0; nf < 2; ++nf) {
        int cn = n0 + wn + nf * 16 + r16;
        float bv = bias[cn];
        #pragma unroll
        for (int mf = 0; mf < 4; ++mf) {
            #pragma unroll
            for (int r = 0; r < 4; ++r) {
                int row = m0 + wm + mf * 16 + g * 4 + r;
                if (row < M) C[(size_t)row * NC + cn] = acc[mf][nf][r] + bv;
            }
        }
    }
}

// ---------------------------------------------------------------------------
// GATv2 aggregation H=4, C=64: one wave/node, pipelined gather,
// first-edge-shift softmax (shift-invariant, no online rescale)
// ---------------------------------------------------------------------------
__global__ __launch_bounds__(256) void gat_agg4(const float* __restrict__ xl,
                                                const float* __restrict__ xr,
                                                const float* __restrict__ att,
                                                const float* __restrict__ bias,
                                                const int* __restrict__ rowptr,
                                                const int* __restrict__ col,
                                                float* __restrict__ out, int N) {
    int i = blockIdx.x * 4 + (threadIdx.x >> 6);
    int lane = threadIdx.x & 63;
    if (i >= N) return;
    const float4 xr4 = *(const float4*)(xr + (size_t)i * 256 + lane * 4);
    const float4 atp = *(const float4*)(att + lane * 4);
    float4 atm;
    atm.x = atp.x * 0.2f; atm.y = atp.y * 0.2f;
    atm.z = atp.z * 0.2f; atm.w = atp.w * 0.2f;
    int e0 = rowptr[i], e1 = rowptr[i + 1];
    int nE = e1 - e0;  // >= 1 (self-loop)

    auto score = [&](const float4& gv) -> float {
        float t0 = gv.x + xr4.x, t1 = gv.y + xr4.y, t2 = gv.z + xr4.z, t3 = gv.w + xr4.w;
        float s;
        s  = fmaxf(t0, 0.f) * atp.x + fminf(t0, 0.f) * atm.x;
        s += fmaxf(t1, 0.f) * atp.y + fminf(t1, 0.f) * atm.y;
        s += fmaxf(t2, 0.f) * atp.z + fminf(t2, 0.f) * atm.z;
        s += fmaxf(t3, 0.f) * atp.w + fminf(t3, 0.f) * atm.w;
        s += __shfl_xor(s, 1);
        s += __shfl_xor(s, 2);
        s += __shfl_xor(s, 4);
        s += __shfl_xor(s, 8);
        return s;
    };

    int c0 = col[e0];
    int c1 = (nE > 1) ? col[e0 + 1] : c0;
    float4 r0 = *(const float4*)(xl + (size_t)c0 * 256 + lane * 4);
    float4 r1 = (nE > 1) ? *(const float4*)(xl + (size_t)c1 * 256 + lane * 4) : r0;

    float m = score(r0);   // shift = first edge's score; p0 = 1
    float ssum = 1.f;
    float4 acc = r0;
    int c2 = (nE > 2) ? col[e0 + 2] : 0;
    for (int t = 1; t < nE; ++t) {
        float4 rn = r0;
        if (t + 1 < nE) rn = *(const float4*)(xl + (size_t)c2 * 256 + lane * 4);
        int c3 = (t + 2 < nE) ? col[e0 + t + 2] : 0;
        float s = score(r1);
        float p = __expf(s - m);
        ssum += p;
        acc.x += p * r1.x; acc.y += p * r1.y;
        acc.z += p * r1.z; acc.w += p * r1.w;
        r1 = rn; c2 = c3;
    }
    float inv = 1.f / ssum;
    const float4 bv = *(const float4*)(bias + lane * 4);
    float o0 = acc.x * inv + bv.x;
    float o1 = acc.y * inv + bv.y;
    float o2 = acc.z * inv + bv.z;
    float o3 = acc.w * inv + bv.w;
    o0 = o0 > 0.f ? o0 : __expf(o0) - 1.f;
    o1 = o1 > 0.f ? o1 : __expf(o1) - 1.f;
    o2 = o2 > 0.f ? o2 : __expf(o2) - 1.f;
    o3 = o3 > 0.f ? o3 : __expf(o3) - 1.f;
    *(float4*)(out + (size_t)i * 256 + lane * 4) = make_float4(o0, o1, o2, o3);
}

// ---------------------------------------------------------------------------
// GATv2 aggregation H=1, C=64 (layer 3) + FC [64->2], pipelined
// ---------------------------------------------------------------------------
__global__ __launch_bounds__(256) void gat_agg1_fc(const float* __restrict__ xl,
                                                   const float* __restrict__ xr,
                                                   const float* __restrict__ att,
                                                   const float* __restrict__ bias,
                                                   const float* __restrict__ Wfc,
                                                   const float* __restrict__ bfc,
                                                   const int* __restrict__ rowptr,
                                                   const int* __restrict__ col,
                                                   float* __restrict__ out, int N) {
    int i = blockIdx.x * 4 + (threadIdx.x >> 6);
    int lane = threadIdx.x & 63;
    if (i >= N) return;
    float xrv = xr[(size_t)i * 64 + lane];
    float atv = att[lane];
    float atm = atv * 0.2f;
    int e0 = rowptr[i], e1 = rowptr[i + 1];
    int nE = e1 - e0;

    auto score = [&](float gv) -> float {
        float t = gv + xrv;
        float s = fmaxf(t, 0.f) * atv + fminf(t, 0.f) * atm;
        s += __shfl_xor(s, 1);
        s += __shfl_xor(s, 2);
        s += __shfl_xor(s, 4);
        s += __shfl_xor(s, 8);
        s += __shfl_xor(s, 16);
        s += __shfl_xor(s, 32);
        return s;
    };

    int c0 = col[e0];
    int c1 = (nE > 1) ? col[e0 + 1] : c0;
    float r0v = xl[(size_t)c0 * 64 + lane];
    float r1v = (nE > 1) ? xl[(size_t)c1 * 64 + lane] : r0v;

    float m = score(r0v);
    float ssum = 1.f, acc = r0v;
    int c2 = (nE > 2) ? col[e0 + 2] : 0;
    for (int t = 1; t < nE; ++t) {
        float rnv = r0v;
        if (t + 1 < nE) rnv = xl[(size_t)c2 * 64 + lane];
        int c3 = (t + 2 < nE) ? col[e0 + t + 2] : 0;
        float s = score(r1v);
        float p = __expf(s - m);
        ssum += p;
        acc = fmaf(p, r1v, acc);
        r1v = rnv; c2 = c3;
    }
    float h = acc / ssum + bias[lane];
    float q0 = h * Wfc[lane * 2 + 0];
    float q1 = h * Wfc[lane * 2 + 1];
    #pragma unroll
    for (int off = 1; off < 64; off <<= 1) {
        q0 += __shfl_xor(q0, off);
        q1 += __shfl_xor(q1, off);
    }
    if (lane == 0) {
        out[(size_t)i * 2 + 0] = q0 + bfc[0];
        out[(size_t)i * 2 + 1] = q1 + bfc[1];
    }
}

// ---------------------------------------------------------------------------
extern "C" void kernel_launch(void* const* d_in, const int* in_sizes, int n_in,
                              void* d_out, int out_size, void* d_ws, size_t ws_size,
                              hipStream_t stream) {
    const float* x    = (const float*)d_in[0];
    const int*   ei   = (const int*)d_in[1];
    const float* Wl1  = (const float*)d_in[2];
    const float* bl1  = (const float*)d_in[3];
    const float* Wr1  = (const float*)d_in[4];
    const float* br1  = (const float*)d_in[5];
    const float* att1 = (const float*)d_in[6];
    const float* b1   = (const float*)d_in[7];
    const float* Wl2  = (const float*)d_in[8];
    const float* bl2  = (const float*)d_in[9];
    const float* Wr2  = (const float*)d_in[10];
    const float* br2  = (const float*)d_in[11];
    const float* att2 = (const float*)d_in[12];
    const float* b2   = (const float*)d_in[13];
    const float* Wl3  = (const float*)d_in[14];
    const float* bl3  = (const float*)d_in[15];
    const float* Wr3  = (const float*)d_in[16];
    const float* br3  = (const float*)d_in[17];
    const float* att3 = (const float*)d_in[18];
    const float* b3   = (const float*)d_in[19];
    const float* Wfc  = (const float*)d_in[20];
    const float* bfc  = (const float*)d_in[21];
    float* out = (float*)d_out;

    const int N = in_sizes[0] / 16;   // 30000
    const int E = in_sizes[1] / 2;    // 480000
    const int* srcp = ei;
    const int* dstp = ei + E;

    char* ws = (char*)d_ws;
    size_t off = 0;
    auto take = [&](size_t bytes) -> char* {
        char* p = ws + off;
        off = (off + bytes + 255) & ~(size_t)255;
        return p;
    };
    int* rowptr = (int*)take((size_t)(N + 1) * 4);
    int* cursor = (int*)take((size_t)N * 4);
    int* deg    = (int*)take((size_t)N * 4);
    int* col    = (int*)take((size_t)(E + N) * 4);
    float* xl   = (float*)take((size_t)N * 256 * 4);
    float* xr   = (float*)take((size_t)N * 256 * 4);
    float* h    = (float*)take((size_t)N * 256 * 4);
    (void)ws_size; (void)n_in; (void)out_size;

    // CSR build
    k_deg_init<<<dim3((N + 255) / 256), dim3(256), 0, stream>>>(deg, N);
    k_count<<<dim3((E + 255) / 256), dim3(256), 0, stream>>>(dstp, E, deg);
    k_scan<<<dim3(1), dim3(1024), 0, stream>>>(deg, rowptr, cursor, N);
    k_scatter<<<dim3((E + N + 255) / 256), dim3(256), 0, stream>>>(srcp, dstp, E, N, cursor, col);

    dim3 agg_grid((N + 3) / 4);
    int mblk = (N + BM - 1) / BM;

    // layer 1 (K=16): f32 VALU GEMM
    gemm_bias<<<dim3((N + 63) / 64, 4), dim3(256), 0, stream>>>(x, Wl1, bl1, xl, N, 16, 256);
    gemm_bias<<<dim3((N + 63) / 64, 4), dim3(256), 0, stream>>>(x, Wr1, br1, xr, N, 16, 256);
    gat_agg4<<<agg_grid, dim3(256), 0, stream>>>(xl, xr, att1, b1, rowptr, col, h, N);

    // layer 2 (K=256): bf16x3 MFMA GEMM
    gemm_mfma<<<dim3(mblk, 4), dim3(256), 0, stream>>>(h, Wl2, bl2, xl, N, 256, 256);
    gemm_mfma<<<dim3(mblk, 4), dim3(256), 0, stream>>>(h, Wr2, br2, xr, N, 256, 256);
    gat_agg4<<<agg_grid, dim3(256), 0, stream>>>(xl, xr, att2, b2, rowptr, col, h, N);

    // layer 3 (K=256, NC=64): MFMA GEMM + fused agg/FC
    gemm_mfma<<<dim3(mblk, 1), dim3(256), 0, stream>>>(h, Wl3, bl3, xl, N, 256, 64);
    gemm_mfma<<<dim3(mblk, 1), dim3(256), 0, stream>>>(h, Wr3, br3, xr, N, 256, 64);
    gat_agg1_fc<<<agg_grid, dim3(256), 0, stream>>>(xl, xr, att3, b3, Wfc, bfc, rowptr, col, out, N);
}

// Round 3
// 375.299 us; speedup vs baseline: 1.4567x; 1.2203x over previous
//
#include <hip/hip_runtime.h>
#include <math.h>

typedef __attribute__((ext_vector_type(8))) short bf16x8;
typedef __attribute__((ext_vector_type(4))) float f32x4;

__device__ inline unsigned short f2bf(float f) {
    union { float f; unsigned u; } v; v.f = f;
    unsigned r = v.u + 0x7FFFu + ((v.u >> 16) & 1u);
    return (unsigned short)(r >> 16);
}
__device__ inline float bf2f(unsigned short s) {
    union { unsigned u; float f; } v; v.u = ((unsigned)s) << 16;
    return v.f;
}

// ---------------------------------------------------------------------------
// CSR construction
// ---------------------------------------------------------------------------
__global__ __launch_bounds__(256) void k_deg_init(int* __restrict__ deg, int N) {
    int i = blockIdx.x * 256 + threadIdx.x;
    if (i < N) deg[i] = 1;  // self-loop
}

__global__ __launch_bounds__(256) void k_count(const int* __restrict__ dst, int E,
                                               int* __restrict__ deg) {
    int e = blockIdx.x * 256 + threadIdx.x;
    if (e < E) atomicAdd(&deg[dst[e]], 1);
}

// 3-phase scan. Phase 1: per-block (1024) exclusive scan, write block sums.
__global__ __launch_bounds__(1024) void k_scan1(const int* __restrict__ deg,
                                                int* __restrict__ excl,
                                                int* __restrict__ bsum, int N) {
    __shared__ int wsum[17];
    int t = threadIdx.x, lane = t & 63, wid = t >> 6;
    int idx = blockIdx.x * 1024 + t;
    int v = (idx < N) ? deg[idx] : 0;
    int x = v;
    #pragma unroll
    for (int off = 1; off < 64; off <<= 1) {
        int y = __shfl_up(x, off, 64);
        if (lane >= off) x += y;
    }
    if (lane == 63) wsum[wid] = x;
    __syncthreads();
    if (wid == 0 && lane < 16) {
        int w = wsum[lane];
        int xs = w;
        #pragma unroll
        for (int off = 1; off < 16; off <<= 1) {
            int y = __shfl_up(xs, off, 64);
            if (lane >= off) xs += y;
        }
        wsum[lane] = xs - w;
        if (lane == 15) wsum[16] = xs;
    }
    __syncthreads();
    int incl = x + wsum[wid];
    if (idx < N) excl[idx] = incl - v;
    if (t == 0) bsum[blockIdx.x] = wsum[16];
}

// Phase 2: single wave scans block sums (nb <= 64), in-place -> exclusive, [nb]=total
__global__ __launch_bounds__(64) void k_scan2(int* __restrict__ bsum, int nb) {
    int lane = threadIdx.x;
    int v = (lane < nb) ? bsum[lane] : 0;
    int x = v;
    #pragma unroll
    for (int off = 1; off < 64; off <<= 1) {
        int y = __shfl_up(x, off, 64);
        if (lane >= off) x += y;
    }
    if (lane < nb) bsum[lane] = x - v;
    if (lane == 63) bsum[nb] = x;
}

// Phase 3: add block offset, write rowptr + cursor
__global__ __launch_bounds__(1024) void k_scan3(const int* __restrict__ excl,
                                                const int* __restrict__ bsum,
                                                int* __restrict__ rowptr,
                                                int* __restrict__ cursor, int N, int nb) {
    int idx = blockIdx.x * 1024 + threadIdx.x;
    if (idx < N) {
        int e = excl[idx] + bsum[blockIdx.x];
        rowptr[idx] = e;
        cursor[idx] = e;
    }
    if (idx == 0) rowptr[N] = bsum[nb];
}

__global__ __launch_bounds__(256) void k_scatter(const int* __restrict__ src,
                                                 const int* __restrict__ dst,
                                                 int E, int N,
                                                 int* __restrict__ cursor,
                                                 int* __restrict__ col) {
    int idx = blockIdx.x * 256 + threadIdx.x;
    if (idx < E) {
        int d = dst[idx];
        int pos = atomicAdd(&cursor[d], 1);
        col[pos] = src[idx];
    } else if (idx < E + N) {
        int i = idx - E;
        int pos = atomicAdd(&cursor[i], 1);
        col[pos] = i;
    }
}

// ---------------------------------------------------------------------------
// f32 GEMM, dual-weight (layer 1, K=16): C1 = A@W1+b1, C2 = A@W2+b2
// ---------------------------------------------------------------------------
__global__ __launch_bounds__(256) void gemm_bias2(const float* __restrict__ A,
                                                  const float* __restrict__ W1,
                                                  const float* __restrict__ b1,
                                                  const float* __restrict__ W2,
                                                  const float* __restrict__ b2,
                                                  float* __restrict__ C1,
                                                  float* __restrict__ C2,
                                                  int M, int K, int NC) {
    __shared__ float As[16][68];
    __shared__ float Bs[2][16][68];
    int tid = threadIdx.x;
    int tx = tid & 15, ty = tid >> 4;
    int m0 = blockIdx.x * 64, n0 = blockIdx.y * 64;
    float acc[2][4][4] = {};
    for (int k0 = 0; k0 < K; k0 += 16) {
        #pragma unroll
        for (int i = 0; i < 4; ++i) {
            int idx = tid + i * 256;
            int r = idx >> 4, c = idx & 15;
            int row = m0 + r;
            As[c][r] = (row < M) ? A[(size_t)row * K + k0 + c] : 0.f;
        }
        #pragma unroll
        for (int i = 0; i < 4; ++i) {
            int idx = tid + i * 256;
            int r = idx >> 6, c = idx & 63;
            Bs[0][r][c] = W1[(size_t)(k0 + r) * NC + n0 + c];
            Bs[1][r][c] = W2[(size_t)(k0 + r) * NC + n0 + c];
        }
        __syncthreads();
        #pragma unroll
        for (int k = 0; k < 16; ++k) {
            float a[4], b[4], b2v[4];
            #pragma unroll
            for (int i = 0; i < 4; ++i) a[i] = As[k][ty * 4 + i];
            #pragma unroll
            for (int i = 0; i < 4; ++i) b[i] = Bs[0][k][tx * 4 + i];
            #pragma unroll
            for (int i = 0; i < 4; ++i) b2v[i] = Bs[1][k][tx * 4 + i];
            #pragma unroll
            for (int i = 0; i < 4; ++i)
                #pragma unroll
                for (int j = 0; j < 4; ++j) {
                    acc[0][i][j] += a[i] * b[j];
                    acc[1][i][j] += a[i] * b2v[j];
                }
        }
        __syncthreads();
    }
    #pragma unroll
    for (int i = 0; i < 4; ++i) {
        int row = m0 + ty * 4 + i;
        if (row < M) {
            #pragma unroll
            for (int j = 0; j < 4; ++j) {
                int cn = n0 + tx * 4 + j;
                C1[(size_t)row * NC + cn] = acc[0][i][j] + b1[cn];
                C2[(size_t)row * NC + cn] = acc[1][i][j] + b2[cn];
            }
        }
    }
}

// ---------------------------------------------------------------------------
// bf16x3 split MFMA GEMM, dual-weight: C1 = A@W1+b1, C2 = A@W2+b2
// BM=128, BN=64, BK=32; A staged (and converted) once per k-tile.
// ---------------------------------------------------------------------------
#define BM 128
#define BN 64
#define BKK 32
#define LDK 40

__global__ __launch_bounds__(256) void gemm_mfma2(const float* __restrict__ A,
                                                  const float* __restrict__ W1,
                                                  const float* __restrict__ b1,
                                                  const float* __restrict__ W2,
                                                  const float* __restrict__ b2,
                                                  float* __restrict__ C1,
                                                  float* __restrict__ C2,
                                                  int M, int K, int NC) {
    __shared__ unsigned short Ah[BM * LDK], Al[BM * LDK];
    __shared__ unsigned short Bh[2][BN * LDK], Bl[2][BN * LDK];
    int tid = threadIdx.x;
    int lane = tid & 63;
    int wid = tid >> 6;
    int m0 = blockIdx.x * BM;
    int n0 = blockIdx.y * BN;
    int wm = (wid >> 1) * 64;
    int wn = (wid & 1) * 32;
    int r16 = lane & 15;
    int g8 = (lane >> 4) * 8;

    f32x4 acc[2][4][2];
    #pragma unroll
    for (int w = 0; w < 2; ++w)
        #pragma unroll
        for (int a = 0; a < 4; ++a)
            #pragma unroll
            for (int b = 0; b < 2; ++b)
                #pragma unroll
                for (int q = 0; q < 4; ++q) acc[w][a][b][q] = 0.f;

    for (int k0 = 0; k0 < K; k0 += BKK) {
        #pragma unroll
        for (int p = 0; p < 4; ++p) {
            int r = (tid >> 3) + 32 * p;
            int kq = (tid & 7) * 4;
            int row = m0 + r;
            float4 v = make_float4(0.f, 0.f, 0.f, 0.f);
            if (row < M) v = *(const float4*)(A + (size_t)row * K + k0 + kq);
            ushort4 hv, lv;
            hv.x = f2bf(v.x); lv.x = f2bf(v.x - bf2f(hv.x));
            hv.y = f2bf(v.y); lv.y = f2bf(v.y - bf2f(hv.y));
            hv.z = f2bf(v.z); lv.z = f2bf(v.z - bf2f(hv.z));
            hv.w = f2bf(v.w); lv.w = f2bf(v.w - bf2f(hv.w));
            *(ushort4*)&Ah[r * LDK + kq] = hv;
            *(ushort4*)&Al[r * LDK + kq] = lv;
        }
        #pragma unroll
        for (int p = 0; p < 2; ++p) {
            int kr = (tid >> 4) + 16 * p;
            int nq = (tid & 15) * 4;
            float4 v1 = *(const float4*)(W1 + (size_t)(k0 + kr) * NC + n0 + nq);
            float4 v2 = *(const float4*)(W2 + (size_t)(k0 + kr) * NC + n0 + nq);
            #pragma unroll
            for (int q = 0; q < 4; ++q) {
                float f1 = (&v1.x)[q];
                unsigned short h1 = f2bf(f1);
                Bh[0][(nq + q) * LDK + kr] = h1;
                Bl[0][(nq + q) * LDK + kr] = f2bf(f1 - bf2f(h1));
                float f2 = (&v2.x)[q];
                unsigned short h2 = f2bf(f2);
                Bh[1][(nq + q) * LDK + kr] = h2;
                Bl[1][(nq + q) * LDK + kr] = f2bf(f2 - bf2f(h2));
            }
        }
        __syncthreads();
        bf16x8 ah[4], al[4];
        #pragma unroll
        for (int mf = 0; mf < 4; ++mf) {
            int base = (wm + mf * 16 + r16) * LDK + g8;
            ah[mf] = *(const bf16x8*)&Ah[base];
            al[mf] = *(const bf16x8*)&Al[base];
        }
        #pragma unroll
        for (int w = 0; w < 2; ++w) {
            bf16x8 bh[2], bl[2];
            #pragma unroll
            for (int nf = 0; nf < 2; ++nf) {
                int base = (wn + nf * 16 + r16) * LDK + g8;
                bh[nf] = *(const bf16x8*)&Bh[w][base];
                bl[nf] = *(const bf16x8*)&Bl[w][base];
            }
            #pragma unroll
            for (int mf = 0; mf < 4; ++mf)
                #pragma unroll
                for (int nf = 0; nf < 2; ++nf) {
                    acc[w][mf][nf] = __builtin_amdgcn_mfma_f32_16x16x32_bf16(ah[mf], bh[nf], acc[w][mf][nf], 0, 0, 0);
                    acc[w][mf][nf] = __builtin_amdgcn_mfma_f32_16x16x32_bf16(ah[mf], bl[nf], acc[w][mf][nf], 0, 0, 0);
                    acc[w][mf][nf] = __builtin_amdgcn_mfma_f32_16x16x32_bf16(al[mf], bh[nf], acc[w][mf][nf], 0, 0, 0);
                }
        }
        __syncthreads();
    }
    int g = lane >> 4;
    #pragma unroll
    for (int nf = 0; nf < 2; ++nf) {
        int cn = n0 + wn + nf * 16 + r16;
        float bv1 = b1[cn], bv2 = b2[cn];
        #pragma unroll
        for (int mf = 0; mf < 4; ++mf) {
            #pragma unroll
            for (int r = 0; r < 4; ++r) {
                int row = m0 + wm + mf * 16 + g * 4 + r;
                if (row < M) {
                    C1[(size_t)row * NC + cn] = acc[0][mf][nf][r] + bv1;
                    C2[(size_t)row * NC + cn] = acc[1][mf][nf][r] + bv2;
                }
            }
        }
    }
}

// ---------------------------------------------------------------------------
// GATv2 aggregation H=4, C=64: one wave/node, 8-deep pipelined gather,
// first-edge-shift softmax.
// ---------------------------------------------------------------------------
__global__ __launch_bounds__(256) void gat_agg4(const float* __restrict__ xl,
                                                const float* __restrict__ xr,
                                                const float* __restrict__ att,
                                                const float* __restrict__ bias,
                                                const int* __restrict__ rowptr,
                                                const int* __restrict__ col,
                                                float* __restrict__ out, int N) {
    int i = blockIdx.x * 4 + (threadIdx.x >> 6);
    int lane = threadIdx.x & 63;
    if (i >= N) return;
    const float4 xr4 = *(const float4*)(xr + (size_t)i * 256 + lane * 4);
    const float4 atp = *(const float4*)(att + lane * 4);
    float4 atm;
    atm.x = atp.x * 0.2f; atm.y = atp.y * 0.2f;
    atm.z = atp.z * 0.2f; atm.w = atp.w * 0.2f;
    int e0 = rowptr[i], e1 = rowptr[i + 1];
    int nE = e1 - e0;  // >= 1 (self-loop)

    auto cidx = [&](int t) -> int { return col[e0 + (t < nE ? t : nE - 1)]; };
    auto ld = [&](int j) -> float4 {
        return *(const float4*)(xl + (size_t)j * 256 + lane * 4);
    };
    auto score = [&](const float4& gv) -> float {
        float t0 = gv.x + xr4.x, t1 = gv.y + xr4.y, t2 = gv.z + xr4.z, t3 = gv.w + xr4.w;
        float s;
        s  = fmaxf(t0, 0.f) * atp.x + fminf(t0, 0.f) * atm.x;
        s += fmaxf(t1, 0.f) * atp.y + fminf(t1, 0.f) * atm.y;
        s += fmaxf(t2, 0.f) * atp.z + fminf(t2, 0.f) * atm.z;
        s += fmaxf(t3, 0.f) * atp.w + fminf(t3, 0.f) * atm.w;
        s += __shfl_xor(s, 1);
        s += __shfl_xor(s, 2);
        s += __shfl_xor(s, 4);
        s += __shfl_xor(s, 8);
        return s;
    };

    // prologue: 8 rows in flight, 4 indices ahead
    int j0 = cidx(0), j1 = cidx(1), j2 = cidx(2), j3 = cidx(3);
    float4 r0 = ld(j0), r1 = ld(j1), r2 = ld(j2), r3 = ld(j3);
    int j4 = cidx(4), j5 = cidx(5), j6 = cidx(6), j7 = cidx(7);
    float4 r4 = ld(j4), r5 = ld(j5), r6 = ld(j6), r7 = ld(j7);
    j0 = cidx(8); j1 = cidx(9); j2 = cidx(10); j3 = cidx(11);

    float m = score(r0);  // shift = first edge's score
    float ssA = 0.f, ssB = 0.f;
    float4 accA = make_float4(0.f, 0.f, 0.f, 0.f);
    float4 accB = make_float4(0.f, 0.f, 0.f, 0.f);

    #define PROC(R, SS, AC) { \
        float s_ = score(R); \
        float p_ = __expf(s_ - m); \
        SS += p_; \
        AC.x = fmaf(p_, R.x, AC.x); AC.y = fmaf(p_, R.y, AC.y); \
        AC.z = fmaf(p_, R.z, AC.z); AC.w = fmaf(p_, R.w, AC.w); }

    int t = 0;
    while (t + 8 <= nE) {
        // phase A: process edges t..t+3, reload with t+8..t+11
        PROC(r0, ssA, accA); PROC(r1, ssB, accB);
        PROC(r2, ssA, accA); PROC(r3, ssB, accB);
        r0 = ld(j0); r1 = ld(j1); r2 = ld(j2); r3 = ld(j3);
        j0 = cidx(t + 12); j1 = cidx(t + 13); j2 = cidx(t + 14); j3 = cidx(t + 15);
        // phase B: process edges t+4..t+7, reload with t+12..t+15
        PROC(r4, ssA, accA); PROC(r5, ssB, accB);
        PROC(r6, ssA, accA); PROC(r7, ssB, accB);
        r4 = ld(j0); r5 = ld(j1); r6 = ld(j2); r7 = ld(j3);
        j0 = cidx(t + 16); j1 = cidx(t + 17); j2 = cidx(t + 18); j3 = cidx(t + 19);
        t += 8;
    }
    // tail: up to 7 edges in r0..r7 (wave-uniform guards)
    if (t + 0 < nE) PROC(r0, ssA, accA);
    if (t + 1 < nE) PROC(r1, ssB, accB);
    if (t + 2 < nE) PROC(r2, ssA, accA);
    if (t + 3 < nE) PROC(r3, ssB, accB);
    if (t + 4 < nE) PROC(r4, ssA, accA);
    if (t + 5 < nE) PROC(r5, ssB, accB);
    if (t + 6 < nE) PROC(r6, ssA, accA);
    if (t + 7 < nE) PROC(r7, ssB, accB);
    #undef PROC

    float inv = 1.f / (ssA + ssB);
    float4 acc;
    acc.x = accA.x + accB.x; acc.y = accA.y + accB.y;
    acc.z = accA.z + accB.z; acc.w = accA.w + accB.w;
    const float4 bv = *(const float4*)(bias + lane * 4);
    float o0 = acc.x * inv + bv.x;
    float o1 = acc.y * inv + bv.y;
    float o2 = acc.z * inv + bv.z;
    float o3 = acc.w * inv + bv.w;
    o0 = o0 > 0.f ? o0 : __expf(o0) - 1.f;
    o1 = o1 > 0.f ? o1 : __expf(o1) - 1.f;
    o2 = o2 > 0.f ? o2 : __expf(o2) - 1.f;
    o3 = o3 > 0.f ? o3 : __expf(o3) - 1.f;
    *(float4*)(out + (size_t)i * 256 + lane * 4) = make_float4(o0, o1, o2, o3);
}

// ---------------------------------------------------------------------------
// GATv2 aggregation H=1, C=64 (layer 3) + FC [64->2], 8-deep pipelined
// ---------------------------------------------------------------------------
__global__ __launch_bounds__(256) void gat_agg1_fc(const float* __restrict__ xl,
                                                   const float* __restrict__ xr,
                                                   const float* __restrict__ att,
                                                   const float* __restrict__ bias,
                                                   const float* __restrict__ Wfc,
                                                   const float* __restrict__ bfc,
                                                   const int* __restrict__ rowptr,
                                                   const int* __restrict__ col,
                                                   float* __restrict__ out, int N) {
    int i = blockIdx.x * 4 + (threadIdx.x >> 6);
    int lane = threadIdx.x & 63;
    if (i >= N) return;
    float xrv = xr[(size_t)i * 64 + lane];
    float atv = att[lane];
    float atm = atv * 0.2f;
    int e0 = rowptr[i], e1 = rowptr[i + 1];
    int nE = e1 - e0;

    auto cidx = [&](int t) -> int { return col[e0 + (t < nE ? t : nE - 1)]; };
    auto ld = [&](int j) -> float { return xl[(size_t)j * 64 + lane]; };
    auto score = [&](float gv) -> float {
        float tv = gv + xrv;
        float s = fmaxf(tv, 0.f) * atv + fminf(tv, 0.f) * atm;
        s += __shfl_xor(s, 1);
        s += __shfl_xor(s, 2);
        s += __shfl_xor(s, 4);
        s += __shfl_xor(s, 8);
        s += __shfl_xor(s, 16);
        s += __shfl_xor(s, 32);
        return s;
    };

    int j0 = cidx(0), j1 = cidx(1), j2 = cidx(2), j3 = cidx(3);
    float r0 = ld(j0), r1 = ld(j1), r2 = ld(j2), r3 = ld(j3);
    int j4 = cidx(4), j5 = cidx(5), j6 = cidx(6), j7 = cidx(7);
    float r4 = ld(j4), r5 = ld(j5), r6 = ld(j6), r7 = ld(j7);
    j0 = cidx(8); j1 = cidx(9); j2 = cidx(10); j3 = cidx(11);

    float m = score(r0);
    float ssA = 0.f, ssB = 0.f, accA = 0.f, accB = 0.f;

    #define PROC1(R, SS, AC) { \
        float s_ = score(R); \
        float p_ = __expf(s_ - m); \
        SS += p_; AC = fmaf(p_, R, AC); }

    int t = 0;
    while (t + 8 <= nE) {
        PROC1(r0, ssA, accA); PROC1(r1, ssB, accB);
        PROC1(r2, ssA, accA); PROC1(r3, ssB, accB);
        r0 = ld(j0); r1 = ld(j1); r2 = ld(j2); r3 = ld(j3);
        j0 = cidx(t + 12); j1 = cidx(t + 13); j2 = cidx(t + 14); j3 = cidx(t + 15);
        PROC1(r4, ssA, accA); PROC1(r5, ssB, accB);
        PROC1(r6, ssA, accA); PROC1(r7, ssB, accB);
        r4 = ld(j0); r5 = ld(j1); r6 = ld(j2); r7 = ld(j3);
        j0 = cidx(t + 16); j1 = cidx(t + 17); j2 = cidx(t + 18); j3 = cidx(t + 19);
        t += 8;
    }
    if (t + 0 < nE) PROC1(r0, ssA, accA);
    if (t + 1 < nE) PROC1(r1, ssB, accB);
    if (t + 2 < nE) PROC1(r2, ssA, accA);
    if (t + 3 < nE) PROC1(r3, ssB, accB);
    if (t + 4 < nE) PROC1(r4, ssA, accA);
    if (t + 5 < nE) PROC1(r5, ssB, accB);
    if (t + 6 < nE) PROC1(r6, ssA, accA);
    if (t + 7 < nE) PROC1(r7, ssB, accB);
    #undef PROC1

    float h = (accA + accB) / (ssA + ssB) + bias[lane];
    float q0 = h * Wfc[lane * 2 + 0];
    float q1 = h * Wfc[lane * 2 + 1];
    #pragma unroll
    for (int off = 1; off < 64; off <<= 1) {
        q0 += __shfl_xor(q0, off);
        q1 += __shfl_xor(q1, off);
    }
    if (lane == 0) {
        out[(size_t)i * 2 + 0] = q0 + bfc[0];
        out[(size_t)i * 2 + 1] = q1 + bfc[1];
    }
}

// ---------------------------------------------------------------------------
extern "C" void kernel_launch(void* const* d_in, const int* in_sizes, int n_in,
                              void* d_out, int out_size, void* d_ws, size_t ws_size,
                              hipStream_t stream) {
    const float* x    = (const float*)d_in[0];
    const int*   ei   = (const int*)d_in[1];
    const float* Wl1  = (const float*)d_in[2];
    const float* bl1  = (const float*)d_in[3];
    const float* Wr1  = (const float*)d_in[4];
    const float* br1  = (const float*)d_in[5];
    const float* att1 = (const float*)d_in[6];
    const float* b1   = (const float*)d_in[7];
    const float* Wl2  = (const float*)d_in[8];
    const float* bl2  = (const float*)d_in[9];
    const float* Wr2  = (const float*)d_in[10];
    const float* br2  = (const float*)d_in[11];
    const float* att2 = (const float*)d_in[12];
    const float* b2   = (const float*)d_in[13];
    const float* Wl3  = (const float*)d_in[14];
    const float* bl3  = (const float*)d_in[15];
    const float* Wr3  = (const float*)d_in[16];
    const float* br3  = (const float*)d_in[17];
    const float* att3 = (const float*)d_in[18];
    const float* b3   = (const float*)d_in[19];
    const float* Wfc  = (const float*)d_in[20];
    const float* bfc  = (const float*)d_in[21];
    float* out = (float*)d_out;

    const int N = in_sizes[0] / 16;   // 30000
    const int E = in_sizes[1] / 2;    // 480000
    const int* srcp = ei;
    const int* dstp = ei + E;

    char* ws = (char*)d_ws;
    size_t off = 0;
    auto take = [&](size_t bytes) -> char* {
        char* p = ws + off;
        off = (off + bytes + 255) & ~(size_t)255;
        return p;
    };
    const int nb = (N + 1023) / 1024;
    int* rowptr = (int*)take((size_t)(N + 1) * 4);
    int* cursor = (int*)take((size_t)N * 4);
    int* deg    = (int*)take((size_t)N * 4);
    int* excl   = (int*)take((size_t)N * 4);
    int* bsum   = (int*)take((size_t)(nb + 1) * 4);
    int* col    = (int*)take((size_t)(E + N) * 4);
    float* xl   = (float*)take((size_t)N * 256 * 4);
    float* xr   = (float*)take((size_t)N * 256 * 4);
    float* h    = (float*)take((size_t)N * 256 * 4);
    (void)ws_size; (void)n_in; (void)out_size;

    // CSR build
    k_deg_init<<<dim3((N + 255) / 256), dim3(256), 0, stream>>>(deg, N);
    k_count<<<dim3((E + 255) / 256), dim3(256), 0, stream>>>(dstp, E, deg);
    k_scan1<<<dim3(nb), dim3(1024), 0, stream>>>(deg, excl, bsum, N);
    k_scan2<<<dim3(1), dim3(64), 0, stream>>>(bsum, nb);
    k_scan3<<<dim3(nb), dim3(1024), 0, stream>>>(excl, bsum, rowptr, cursor, N, nb);
    k_scatter<<<dim3((E + N + 255) / 256), dim3(256), 0, stream>>>(srcp, dstp, E, N, cursor, col);

    dim3 agg_grid((N + 3) / 4);
    int mblk = (N + BM - 1) / BM;

    // layer 1 (K=16): fused dual f32 GEMM
    gemm_bias2<<<dim3((N + 63) / 64, 4), dim3(256), 0, stream>>>(
        x, Wl1, bl1, Wr1, br1, xl, xr, N, 16, 256);
    gat_agg4<<<agg_grid, dim3(256), 0, stream>>>(xl, xr, att1, b1, rowptr, col, h, N);

    // layer 2 (K=256): fused dual bf16x3 MFMA GEMM
    gemm_mfma2<<<dim3(mblk, 4), dim3(256), 0, stream>>>(
        h, Wl2, bl2, Wr2, br2, xl, xr, N, 256, 256);
    gat_agg4<<<agg_grid, dim3(256), 0, stream>>>(xl, xr, att2, b2, rowptr, col, h, N);

    // layer 3 (K=256, NC=64): fused dual MFMA GEMM + fused agg/FC
    gemm_mfma2<<<dim3(mblk, 1), dim3(256), 0, stream>>>(
        h, Wl3, bl3, Wr3, br3, xl, xr, N, 256, 64);
    gat_agg1_fc<<<agg_grid, dim3(256), 0, stream>>>(xl, xr, att3, b3, Wfc, bfc, rowptr, col, out, N);
}